// Round 5
// baseline (820.055 us; speedup 1.0000x reference)
//
#include <hip/hip_runtime.h>
#include <hip/hip_bf16.h>
#include <hip/hip_fp16.h>
#include <math.h>

// ---------------------------------------------------------------------------
// ConsisGADGNN fused kernel, round 5: f16 packed atomics for the acc scatter.
// Round-4 counters showed pass1 bound by random RMW bytes on acc
// (FETCH+WRITE ~= 1.1GB at 1.6TB/s ~= measured 697us). acc -> __half,
// scatter via global_atomic_pk_add_f16 (2 channels per atomic), halving
// dirty+fetch bytes and atomic op count. BN stats remain f32-exact.
// ---------------------------------------------------------------------------

#define NTYPES 3
#define CH 64
#define LN_EPS 1e-5f

typedef __attribute__((ext_vector_type(8))) short bf16x8;
typedef __attribute__((ext_vector_type(4))) float f32x4;
typedef __attribute__((ext_vector_type(4))) int i32x4;

// LDS layout (bytes):
//  [0,16K)   W1T bf16 [64 n][128 k], row stride 256B, swz ((n&7)<<4)  (persistent)
//  [16K,32K) X   bf16 [64 e][128 d], row stride 256B, swz ((e&7)<<4)
//            (W2T bf16 [64 n][64 k] staged at 16K..24K pre-loop, then dead)
//  [32K,40K) Hn  bf16 [64 e][64 ch], row stride 128B, swz ((e&7)<<4)
#define W1OFF 0
#define XOFF  16384
#define W2OFF 16384
#define HNOFF 32768
#define LDS_BYTES 40960

__device__ __forceinline__ unsigned short f2bf(float x) {
    __hip_bfloat16 h = __float2bfloat16(x);
    return __builtin_bit_cast(unsigned short, h);
}
__device__ __forceinline__ unsigned pack2(float lo, float hi) {
    return (unsigned)f2bf(lo) | ((unsigned)f2bf(hi) << 16);
}
__device__ __forceinline__ float elu(float x) {
    return x > 0.f ? x : (__expf(x) - 1.0f);
}

// MODE 0: scatter raw p (f16 pk atomics) + cnt + BN stats (fast path)
// MODE 1: BN stats only (fallback pass A)
// MODE 2: scatter normalized p (f32) into [N][64] (fallback pass B)
template <int MODE>
__global__ __launch_bounds__(256, 2) void pass1_kernel(
    const float* __restrict__ feat,
    const float* __restrict__ W1, const float* __restrict__ b1,
    const float* __restrict__ lng, const float* __restrict__ lnb,
    const float* __restrict__ W2, const float* __restrict__ b2,
    const int* __restrict__ esrc, const int* __restrict__ edst,
    int N, int E,
    void* __restrict__ accv, int* __restrict__ cnt,
    float* __restrict__ ssum, float* __restrict__ ssq,
    const float* __restrict__ scale, const float* __restrict__ shift)
{
    __shared__ __align__(16) unsigned char lds[LDS_BYTES];
#define LDS16(o) (*(unsigned short*)(lds + (o)))
#define LDS32(o) (*(unsigned*)(lds + (o)))
#define LDSV(o)  (*(i32x4*)(lds + (o)))

    __half* acc16 = (__half*)accv;   // MODE 0
    float*  accf  = (float*)accv;    // MODE 2

    const int tid  = threadIdx.x;
    const int lane = tid & 63;
    const int w    = tid >> 6;     // wave 0..3
    const int g    = lane >> 4;    // 16-lane group 0..3
    const int c    = lane & 15;
    const int t    = blockIdx.x % NTYPES;
    const int bpt  = gridDim.x / NTYPES;
    const int nTiles = (E + 63) >> 6;

    const float* W1t = W1 + (size_t)t * 128 * CH;
    const float* W2t = W2 + (size_t)t * CH * CH;
    const size_t ebase = (size_t)t * E;
    const float2* feat2 = (const float2*)feat;

    // ---- stage W1^T and W2^T into LDS as bf16 (once per block) ----
    #pragma unroll 4
    for (int it = 0; it < 32; ++it) {
        int id = it * 256 + tid;            // 8192 = 128k x 64n, coalesced over n
        int k = id >> 6, n = id & 63;
        LDS16(W1OFF + n * 256 + ((k * 2) ^ ((n & 7) << 4))) = f2bf(W1t[id]);
    }
    #pragma unroll 4
    for (int it = 0; it < 16; ++it) {
        int id = it * 256 + tid;            // 4096 = 64k x 64n
        int k = id >> 6, n = id & 63;
        LDS16(W2OFF + n * 128 + ((k * 2) ^ ((n & 7) << 4))) = f2bf(W2t[id]);
    }
    __syncthreads();
    // ---- hoist W2 B-frags to registers: [nb][kb] ----
    bf16x8 w2f[4][2];
    #pragma unroll
    for (int nb = 0; nb < 4; ++nb)
        #pragma unroll
        for (int kb = 0; kb < 2; ++kb) {
            int n = nb * 16 + c;
            w2f[nb][kb] = __builtin_bit_cast(bf16x8,
                LDSV(W2OFF + n * 128 + ((kb * 64 + g * 16) ^ ((n & 7) << 4))));
        }
    __syncthreads();   // W2T region becomes X region

    // per-lane channel params (ch = nb*16 + c)
    float b1v[4], b2v[4], lngv[4], lnbv[4], scv[4], shv[4];
    #pragma unroll
    for (int nb = 0; nb < 4; ++nb) {
        int ch = nb * 16 + c;
        b1v[nb]  = b1[t * CH + ch];
        b2v[nb]  = b2[t * CH + ch];
        lngv[nb] = lng[t * CH + ch];
        lnbv[nb] = lnb[t * CH + ch];
        if (MODE == 2) { scv[nb] = scale[t * CH + ch]; shv[nb] = shift[t * CH + ch]; }
    }
    float rs[4] = {0, 0, 0, 0}, rq[4] = {0, 0, 0, 0};

    // =================== barrier-free main loop ===================
    for (int tile = blockIdx.x / NTYPES; tile < nTiles; tile += bpt) {
        const int e0 = (tile << 6) + w * 16;     // this wave's 16 edges
        // ---- indices: lanes 0..15 src, 16..31 dst ----
        int idxv = 0;
        if (lane < 16)      { int ge = e0 + lane;       idxv = (ge < E) ? esrc[ebase + ge] : 0; }
        else if (lane < 32) { int ge = e0 + (lane & 15); idxv = (ge < E) ? edst[ebase + ge] : 0; }
        // ---- stage X rows (wave-private) ----
        const int xin = (lane & 31) * 4 + (lane >> 5) * 128;   // byte within 256B row
        #pragma unroll
        for (int k = 0; k < 16; ++k) {
            int srck = __shfl(idxv, k);
            int dstk = __shfl(idxv, 16 + k);
            int row  = (lane < 32) ? srck : dstk;
            float2 v = feat2[(size_t)row * 32 + (lane & 31)];
            int e = w * 16 + k;
            LDS32(XOFF + e * 256 + (xin ^ ((e & 7) << 4))) = pack2(v.x, v.y);
        }
        // ---- layer 1: h = X @ W1 + b1 (A rows wave-private) ----
        f32x4 hacc[4];
        #pragma unroll
        for (int nb = 0; nb < 4; ++nb) hacc[nb] = (f32x4){b1v[nb], b1v[nb], b1v[nb], b1v[nb]};
        const int xrow = w * 16 + c;
        #pragma unroll
        for (int kb = 0; kb < 4; ++kb) {
            bf16x8 a = __builtin_bit_cast(bf16x8,
                LDSV(XOFF + xrow * 256 + ((kb * 64 + g * 16) ^ ((xrow & 7) << 4))));
            #pragma unroll
            for (int nb = 0; nb < 4; ++nb) {
                int n = nb * 16 + c;
                bf16x8 b = __builtin_bit_cast(bf16x8,
                    LDSV(W1OFF + n * 256 + ((kb * 64 + g * 16) ^ ((n & 7) << 4))));
                hacc[nb] = __builtin_amdgcn_mfma_f32_16x16x32_bf16(a, b, hacc[nb], 0, 0, 0);
            }
        }
        // ---- ELU + LayerNorm, fully in-register ----
        float sI[4] = {0, 0, 0, 0}, qI[4] = {0, 0, 0, 0};
        #pragma unroll
        for (int nb = 0; nb < 4; ++nb)
            #pragma unroll
            for (int i = 0; i < 4; ++i) {
                float h = elu(hacc[nb][i]);
                hacc[nb][i] = h;
                sI[i] += h; qI[i] += h * h;
            }
        #pragma unroll
        for (int i = 0; i < 4; ++i) {
            float s = sI[i], q = qI[i];
            s += __shfl_xor(s, 1);  q += __shfl_xor(q, 1);
            s += __shfl_xor(s, 2);  q += __shfl_xor(q, 2);
            s += __shfl_xor(s, 4);  q += __shfl_xor(q, 4);
            s += __shfl_xor(s, 8);  q += __shfl_xor(q, 8);
            float mean = s * (1.f / 64.f);
            float var  = q * (1.f / 64.f) - mean * mean;
            sI[i] = mean;
            qI[i] = rsqrtf(var + LN_EPS);
        }
        // ---- normalize, write Hn (wave-private rows) ----
        #pragma unroll
        for (int nb = 0; nb < 4; ++nb)
            #pragma unroll
            for (int i = 0; i < 4; ++i) {
                float hn = (hacc[nb][i] - sI[i]) * qI[i] * lngv[nb] + lnbv[nb];
                int row = w * 16 + g * 4 + i;
                int col = nb * 16 + c;
                LDS16(HNOFF + row * 128 + ((col * 2) ^ ((row & 7) << 4))) = f2bf(hn);
            }
        // ---- layer 2: p = Hn @ W2 + b2 ----
        f32x4 pacc[4];
        #pragma unroll
        for (int nb = 0; nb < 4; ++nb) pacc[nb] = (f32x4){b2v[nb], b2v[nb], b2v[nb], b2v[nb]};
        const int hrow = w * 16 + c;
        #pragma unroll
        for (int kb = 0; kb < 2; ++kb) {
            bf16x8 a = __builtin_bit_cast(bf16x8,
                LDSV(HNOFF + hrow * 128 + ((kb * 64 + g * 16) ^ ((hrow & 7) << 4))));
            #pragma unroll
            for (int nb = 0; nb < 4; ++nb)
                pacc[nb] = __builtin_amdgcn_mfma_f32_16x16x32_bf16(a, w2f[nb][kb], pacc[nb], 0, 0, 0);
        }
        // ---- ELU + scatter + BN stats ----
        const int ceven = c & ~1;
        #pragma unroll
        for (int i = 0; i < 4; ++i) {
            int r  = g * 4 + i;
            int ge = e0 + r;
            int dn = __shfl(idxv, 16 + r);
            bool ok = (ge < E);
            float pv4[4], oth[4];
            #pragma unroll
            for (int nb = 0; nb < 4; ++nb) {
                float p = elu(pacc[nb][i]);
                pv4[nb] = p;
                if (ok && MODE <= 1) { rs[nb] += p; rq[nb] += p * p; }
            }
            if (MODE == 0) {
                // exchange with neighbor lane: pair (c even, c odd) holds adjacent channels
                #pragma unroll
                for (int nb = 0; nb < 4; ++nb) oth[nb] = __shfl_xor(pv4[nb], 1);
                if (ok) {
                    const int nb0 = (c & 1) ? 2 : 0;   // even lanes do nb 0,1; odd do 2,3
                    #pragma unroll
                    for (int j = 0; j < 2; ++j) {
                        int nb = nb0 + j;
                        float lo = (c & 1) ? oth[nb] : pv4[nb];   // channel nb*16+ceven
                        float hi = (c & 1) ? pv4[nb] : oth[nb];   // channel nb*16+ceven+1
                        __half2 v = __halves2half2(__float2half(lo), __float2half(hi));
                        unsafeAtomicAdd((__half2*)(acc16 + ((size_t)t * N + dn) * CH + nb * 16 + ceven), v);
                    }
                    if (c == 0) atomicAdd(&cnt[t * N + dn], 1);
                }
            } else if (MODE == 2) {
                if (ok) {
                    #pragma unroll
                    for (int nb = 0; nb < 4; ++nb)
                        atomicAdd(&accf[(size_t)dn * CH + nb * 16 + c], fmaf(pv4[nb], scv[nb], shv[nb]));
                }
            }
        }
    }
    if (MODE <= 1) {
        #pragma unroll
        for (int nb = 0; nb < 4; ++nb) {
            float s = rs[nb] + __shfl_xor(rs[nb], 16);
            s += __shfl_xor(s, 32);
            float q = rq[nb] + __shfl_xor(rq[nb], 16);
            q += __shfl_xor(q, 32);
            if (lane < 16) {
                atomicAdd(&ssum[t * CH + nb * 16 + lane], s);
                atomicAdd(&ssq[t * CH + nb * 16 + lane], q);
            }
        }
    }
#undef LDS16
#undef LDS32
#undef LDSV
}

__global__ void bn_stats_kernel(const float* __restrict__ ssum, const float* __restrict__ ssq,
                                const float* __restrict__ bng, const float* __restrict__ bnb,
                                float* __restrict__ scale, float* __restrict__ shift, float invE)
{
    int i = threadIdx.x;
    if (i < NTYPES * CH) {
        float m  = ssum[i] * invE;
        float v  = ssq[i] * invE - m * m;
        float sc = bng[i] * rsqrtf(v + LN_EPS);
        scale[i] = sc;
        shift[i] = bnb[i] - m * sc;
    }
}

// INPLACE==0: read per-type raw f16 acc + cnt, apply scale/shift, then @Wr + br + feat
// INPLACE==1: d_out already holds normalized segment-sum; apply @Wr + br + feat in place
template <int INPLACE>
__global__ __launch_bounds__(256, 4) void combine_kernel(
    const __half* __restrict__ acc, const int* __restrict__ cnt,
    const float* __restrict__ scale, const float* __restrict__ shift,
    const float* __restrict__ Wr, const float* __restrict__ br,
    const float* __restrict__ feat, float* __restrict__ out, int N)
{
    __shared__ float rowbuf[4][65];
    const int tid = threadIdx.x, lane = tid & 63, w = tid >> 6;
    float wc[64];
    #pragma unroll
    for (int m = 0; m < 64; ++m) wc[m] = Wr[m * CH + lane];   // column `lane`
    float s0 = 0, s1 = 0, s2 = 0, f0 = 0, f1 = 0, f2 = 0;
    if (!INPLACE) {
        s0 = scale[lane];      s1 = scale[CH + lane];  s2 = scale[2 * CH + lane];
        f0 = shift[lane];      f1 = shift[CH + lane];  f2 = shift[2 * CH + lane];
    }
    const float bv = br[lane];
    const int wid = blockIdx.x * 4 + w;
    const int nw  = gridDim.x * 4;
    for (int n = wid; n < N; n += nw) {
        float o;
        if (!INPLACE) {
            o = s0 * __half2float(acc[(size_t)n * CH + lane])           + (float)cnt[n]         * f0
              + s1 * __half2float(acc[((size_t)N + n) * CH + lane])     + (float)cnt[N + n]     * f1
              + s2 * __half2float(acc[((size_t)2 * N + n) * CH + lane]) + (float)cnt[2 * N + n] * f2;
        } else {
            o = out[(size_t)n * CH + lane];
        }
        rowbuf[w][lane] = o;  // wave-private row; in-wave lockstep
        float r = bv + feat[(size_t)n * CH + lane];
        #pragma unroll
        for (int m = 0; m < 64; ++m) r = fmaf(rowbuf[w][m], wc[m], r);
        out[(size_t)n * CH + lane] = r;
    }
}

extern "C" void kernel_launch(void* const* d_in, const int* in_sizes, int n_in,
                              void* d_out, int out_size, void* d_ws, size_t ws_size,
                              hipStream_t stream) {
    const float* feat = (const float*)d_in[0];
    const float* W1   = (const float*)d_in[1];
    const float* b1   = (const float*)d_in[2];
    const float* lng  = (const float*)d_in[3];
    const float* lnb  = (const float*)d_in[4];
    const float* W2   = (const float*)d_in[5];
    const float* b2   = (const float*)d_in[6];
    const float* bng  = (const float*)d_in[7];
    const float* bnb  = (const float*)d_in[8];
    const float* Wr   = (const float*)d_in[9];
    const float* br   = (const float*)d_in[10];
    const int* esrc   = (const int*)d_in[11];
    const int* edst   = (const int*)d_in[12];

    const int N = in_sizes[0] / CH;
    const int E = in_sizes[11] / NTYPES;
    float* out = (float*)d_out;

    const size_t accB  = (size_t)NTYPES * N * CH * sizeof(__half);   // f16 acc
    const size_t cntB  = (size_t)NTYPES * N * sizeof(int);
    const size_t statB = (size_t)NTYPES * CH * sizeof(float);
    const size_t needFast = accB + cntB + 4 * statB;

    const int grid1 = 3072;   // multiple of NTYPES
    const int gridC = 2048;

    if (ws_size >= needFast) {
        char* p = (char*)d_ws;
        __half* acc = (__half*)p; p += accB;
        int*   cnt  = (int*)p;    p += cntB;
        float* ssum = (float*)p;  p += statB;
        float* ssq  = (float*)p;  p += statB;
        float* scl  = (float*)p;  p += statB;
        float* shf  = (float*)p;

        hipMemsetAsync(d_ws, 0, accB + cntB + 2 * statB, stream);
        pass1_kernel<0><<<grid1, 256, 0, stream>>>(feat, W1, b1, lng, lnb, W2, b2,
                                                   esrc, edst, N, E,
                                                   acc, cnt, ssum, ssq, nullptr, nullptr);
        bn_stats_kernel<<<1, 192, 0, stream>>>(ssum, ssq, bng, bnb, scl, shf, 1.0f / (float)E);
        combine_kernel<0><<<gridC, 256, 0, stream>>>(acc, cnt, scl, shf, Wr, br, feat, out, N);
    } else {
        // fallback: tiny ws, two compute passes, accumulate f32 into d_out
        char* p = (char*)d_ws;
        float* ssum = (float*)p;  p += statB;
        float* ssq  = (float*)p;  p += statB;
        float* scl  = (float*)p;  p += statB;
        float* shf  = (float*)p;

        hipMemsetAsync(d_ws, 0, 2 * statB, stream);
        hipMemsetAsync(d_out, 0, (size_t)N * CH * sizeof(float), stream);
        pass1_kernel<1><<<grid1, 256, 0, stream>>>(feat, W1, b1, lng, lnb, W2, b2,
                                                   esrc, edst, N, E,
                                                   nullptr, nullptr, ssum, ssq, nullptr, nullptr);
        bn_stats_kernel<<<1, 192, 0, stream>>>(ssum, ssq, bng, bnb, scl, shf, 1.0f / (float)E);
        pass1_kernel<2><<<grid1, 256, 0, stream>>>(feat, W1, b1, lng, lnb, W2, b2,
                                                   esrc, edst, N, E,
                                                   out, nullptr, nullptr, nullptr, scl, shf);
        combine_kernel<1><<<gridC, 256, 0, stream>>>((const __half*)out, nullptr, nullptr, nullptr,
                                                     Wr, br, feat, out, N);
    }
}